// Round 1
// baseline (3951.098 us; speedup 1.0000x reference)
//
#include <hip/hip_runtime.h>
#include <math.h>

#define NFFT   1024
#define NH     512
#define HOP    64
#define NMELS  80
#define NFR    512
#define NBINS  513
#define NITER  300
#define SIGLEN 33728
#define NSEG   527
#define NT     256
#define NB     512

// ---- workspace layout (4B units) ----
#define TBL_WIN  0          // win[1024]
#define TBL_TWR  1024       // twr[256]
#define TBL_TWI  1280       // twi[256]
#define TBL_W1R  1536       // w1r[513]
#define TBL_W1I  2056       // w1i[513]
#define FGEN     2624       // Fgen[512]  frame-generation flags
#define XGEN     3136       // Xgen[527]  segment-generation flags
#define OFF_MAG  4096       // mag[512*513]
#define OFF_IWS  266752     // iws[33728]
#define OFF_F    300480     // F[512*1024]
#define OFF_X    824768     // x[33792]

typedef unsigned long long u64;
typedef unsigned int u32;

// ---- coherent (agent-scope sc1, L3-point) accessors ----
__device__ __forceinline__ float4 coh_load4(const float* p) {
    u64 a = __hip_atomic_load((const u64*)p,       __ATOMIC_RELAXED, __HIP_MEMORY_SCOPE_AGENT);
    u64 b = __hip_atomic_load((const u64*)(p + 2), __ATOMIC_RELAXED, __HIP_MEMORY_SCOPE_AGENT);
    float2 fa, fb;
    __builtin_memcpy(&fa, &a, 8);
    __builtin_memcpy(&fb, &b, 8);
    return make_float4(fa.x, fa.y, fb.x, fb.y);
}
__device__ __forceinline__ void coh_store4(float* p, float4 v) {
    float2 fa = make_float2(v.x, v.y), fb = make_float2(v.z, v.w);
    u64 a, b;
    __builtin_memcpy(&a, &fa, 8);
    __builtin_memcpy(&b, &fb, 8);
    __hip_atomic_store((u64*)p,       a, __ATOMIC_RELAXED, __HIP_MEMORY_SCOPE_AGENT);
    __hip_atomic_store((u64*)(p + 2), b, __ATOMIC_RELAXED, __HIP_MEMORY_SCOPE_AGENT);
}
__device__ __forceinline__ float coh_load1(const float* p) {
    u32 a = __hip_atomic_load((const u32*)p, __ATOMIC_RELAXED, __HIP_MEMORY_SCOPE_AGENT);
    float f;
    __builtin_memcpy(&f, &a, 4);
    return f;
}
__device__ __forceinline__ void coh_store1(float* p, float v) {
    u32 a;
    __builtin_memcpy(&a, &v, 4);
    __hip_atomic_store((u32*)p, a, __ATOMIC_RELAXED, __HIP_MEMORY_SCOPE_AGENT);
}
__device__ __forceinline__ void flag_store(int* p, int v) {
    __hip_atomic_store(p, v, __ATOMIC_RELAXED, __HIP_MEMORY_SCOPE_AGENT);
}
__device__ __forceinline__ int flag_load(const int* p) {
    return __hip_atomic_load(p, __ATOMIC_RELAXED, __HIP_MEMORY_SCOPE_AGENT);
}

// ---- radix-4 Stockham stage (verified), caller guards tid<128 ----
template<int P, int SH, bool INV>
__device__ __forceinline__ void r4b(const float* __restrict__ sR, const float* __restrict__ sI,
                                    float* __restrict__ dR, float* __restrict__ dI,
                                    const float* twr, const float* twi, int j) {
    int k  = j & (P - 1);
    int d0 = ((j - k) << 2) + k;
    float x0r = sR[j],       x0i = sI[j];
    float x1r = sR[j + 128], x1i = sI[j + 128];
    float x2r = sR[j + 256], x2i = sI[j + 256];
    float x3r = sR[j + 384], x3i = sI[j + 384];
    int tb = k << SH;
    float c1 = twr[tb], s1 = twi[tb];
    if (INV) s1 = -s1;
    float c2 = c1 * c1 - s1 * s1, s2 = 2.f * c1 * s1;
    float c3 = c1 * c2 - s1 * s2, s3 = c1 * s2 + s1 * c2;
    float a1r = x1r * c1 - x1i * s1, a1i = x1r * s1 + x1i * c1;
    float a2r = x2r * c2 - x2i * s2, a2i = x2r * s2 + x2i * c2;
    float a3r = x3r * c3 - x3i * s3, a3i = x3r * s3 + x3i * c3;
    float t0r = x0r + a2r, t0i = x0i + a2i;
    float t1r = x0r - a2r, t1i = x0i - a2i;
    float t2r = a1r + a3r, t2i = a1i + a3i;
    float t3r = a1r - a3r, t3i = a1i - a3i;
    float i3r = INV ? -t3i : t3i;
    float i3i = INV ?  t3r : -t3r;
    dR[d0]         = t0r + t2r;  dI[d0]         = t0i + t2i;
    dR[d0 + P]     = t1r + i3r;  dI[d0 + P]     = t1i + i3i;
    dR[d0 + 2 * P] = t0r - t2r;  dI[d0 + 2 * P] = t0i - t2i;
    dR[d0 + 3 * P] = t1r - i3r;  dI[d0 + 3 * P] = t1i - i3i;
}

// ================= k_init (round-3/5 verified) ===============================
struct __align__(16) SMemI {
    float xb[NFFT];
    float C0r[NH], C0i[NH];
    float C1r[NH], C1i[NH];
    float win[NFFT];
    float twr[256], twi[256];
    float mag[516];
};

extern "C" __global__ __launch_bounds__(NT)
void k_init(const float* __restrict__ mel,
            const float* __restrict__ invmel,
            float* __restrict__ ws) {
    __shared__ SMemI sm;
    const int tid = threadIdx.x;
    const int t   = blockIdx.x;

    for (int n = tid; n < NFFT; n += NT) {
        double a = (2.0 * 3.14159265358979323846) * (double)n / 1024.0;
        sm.win[n] = (float)(0.5 - 0.5 * cos(a));
    }
    for (int j = tid; j < 256; j += NT) {
        double a = (2.0 * 3.14159265358979323846) * (double)j / 512.0;
        sm.twr[j] = (float)cos(a);
        sm.twi[j] = (float)(-sin(a));
    }
    __syncthreads();
    if (t == 0) {
        for (int n = tid; n < NFFT; n += NT) ws[TBL_WIN + n] = sm.win[n];
        for (int j = tid; j < 256; j += NT) {
            ws[TBL_TWR + j] = sm.twr[j];
            ws[TBL_TWI + j] = sm.twi[j];
        }
        for (int k = tid; k < NBINS; k += NT) {
            double a = (2.0 * 3.14159265358979323846) * (double)k / 1024.0;
            ws[TBL_W1R + k] = (float)cos(a);
            ws[TBL_W1I + k] = (float)sin(a);
        }
        // zero neighbor-sync flags: Fgen[512] + Xgen[527] contiguous
        for (int i = tid; i < 512 + NSEG; i += NT)
            ((int*)ws)[FGEN + i] = 0;
    }

    for (int p = t * NT + tid; p < SIGLEN; p += NFR * NT) {
        int tq = p >> 6, io = p & 63;
        float s = 0.f;
#pragma unroll
        for (int m = 0; m < 16; ++m) {
            int tp = tq - m;
            if (tp >= 0 && tp < NFR) {
                float w = sm.win[io + (m << 6)];
                s += w * w;
            }
        }
        ws[OFF_IWS + p] = (s > 1e-11f) ? (1.0f / s) : 1.0f;
    }

    if (tid < NMELS) sm.xb[tid] = exp10f(mel[tid * NFR + t]);
    __syncthreads();
    for (int k = tid; k < NBINS; k += NT) {
        const float* row = invmel + k * NMELS;
        float s = 0.f;
#pragma unroll 8
        for (int j = 0; j < NMELS; ++j) s += row[j] * sm.xb[j];
        ws[OFF_MAG + t * NBINS + k] = s;
        sm.mag[k] = s;
    }
    __syncthreads();

    // A[k] from real X = mag
    for (int k = tid; k < NH; k += NT) {
        float xr = sm.mag[k], yr = sm.mag[512 - k];
        double a = (2.0 * 3.14159265358979323846) * (double)k / 1024.0;
        float c = (float)cos(a), s = (float)sin(a);
        float dr = xr - yr;
        sm.C1r[k] = ((xr + yr) - s * dr) * (1.0f / 1024.0f);
        sm.C1i[k] = (c * dr) * (1.0f / 1024.0f);
    }
    // inverse FFT C1 -> C0
    __syncthreads();
    if (tid < 128) {
        float x0r = sm.C1r[tid],       x0i = sm.C1i[tid];
        float x1r = sm.C1r[tid + 128], x1i = sm.C1i[tid + 128];
        float x2r = sm.C1r[tid + 256], x2i = sm.C1i[tid + 256];
        float x3r = sm.C1r[tid + 384], x3i = sm.C1i[tid + 384];
        float t0r = x0r + x2r, t0i = x0i + x2i;
        float t1r = x0r - x2r, t1i = x0i - x2i;
        float t2r = x1r + x3r, t2i = x1i + x3i;
        float t3r = x1r - x3r, t3i = x1i - x3i;
        float4 vr = make_float4(t0r + t2r, t1r - t3i, t0r - t2r, t1r + t3i);
        float4 vi = make_float4(t0i + t2i, t1i + t3r, t0i - t2i, t1i - t3r);
        ((float4*)sm.C0r)[tid] = vr;
        ((float4*)sm.C0i)[tid] = vi;
    }
    __syncthreads();
    if (tid < 128) r4b<4, 5, true>(sm.C0r, sm.C0i, sm.C1r, sm.C1i, sm.twr, sm.twi, tid);
    __syncthreads();
    if (tid < 128) r4b<16, 3, true>(sm.C1r, sm.C1i, sm.C0r, sm.C0i, sm.twr, sm.twi, tid);
    __syncthreads();
    if (tid < 128) r4b<64, 1, true>(sm.C0r, sm.C0i, sm.C1r, sm.C1i, sm.twr, sm.twi, tid);
    __syncthreads();
    {
        float c = sm.twr[tid], s = -sm.twi[tid];
        float x0r = sm.C1r[tid], x0i = sm.C1i[tid];
        float x1r = sm.C1r[tid + 256], x1i = sm.C1i[tid + 256];
        float ar = x1r * c - x1i * s, ai = x1r * s + x1i * c;
        sm.C0r[tid]       = x0r + ar;  sm.C0i[tid]       = x0i + ai;
        sm.C0r[tid + 256] = x0r - ar;  sm.C0i[tid + 256] = x0i - ai;
    }
    __syncthreads();

    float4 w4 = ((float4*)sm.win)[tid];
    float4 o;
    o.x = w4.x * sm.C0r[2 * tid];
    o.y = w4.y * sm.C0i[2 * tid];
    o.z = w4.z * sm.C0r[2 * tid + 1];
    o.w = w4.w * sm.C0i[2 * tid + 1];
    *(float4*)&ws[OFF_F + (t << 10) + (tid << 2)] = o;
}

// ============== persistent Griffin-Lim: NEIGHBOR-SYNC wavefront pipeline ====
//
// Replaces the two global two-hop barriers per iteration with per-producer
// generation flags. True dependences are local:
//   phase A of block t reads X segs [t, t+15]      -> wait Xgen[t..t+15] >= it
//   phase B for seg s reads frames  [s-15, s]&[0,511] -> wait Fgen[...] >= it
// Release side (proven pattern): sc1 data stores -> __syncthreads (compiler
// drains vmcnt -> data at L3) -> relaxed sc1 flag store.
// WAR safety: overwriting F[t]@it is gated by Xgen[t..t+15]>=it, whose setters
// are exactly the readers of F[t]@it-1; symmetric for X via Fgen. The unrolled
// (iteration, phase) dependence graph is acyclic and flags are monotone, so
// no deadlock and no reset hazard.

struct __align__(16) SM1 {
    float C0r[NH], C0i[NH];
    float C1r[NH], C1i[NH];
    float twr[256], twi[256];
};

extern "C" __global__ __launch_bounds__(NT)
void k_persist(float* __restrict__ ws, float* __restrict__ out) {
    __shared__ SM1 sm;
    const int tid = threadIdx.x;
    const int t   = blockIdx.x;       // frame owned
    const int i0  = tid << 2;
    const int j2  = 512 - tid;
    const int n0  = tid << 1;

    const float* tbl  = ws;
    const float* magg = ws + OFF_MAG;
    const float* iws  = ws + OFF_IWS;
    float* F  = ws + OFF_F;
    float* X  = ws + OFF_X;
    int*   fgen = (int*)ws + FGEN;
    int*   xgen = (int*)ws + XGEN;

    // ---- one-time staging ----
    if (tid < 64)       ((float4*)sm.twr)[tid]      = ((const float4*)(tbl + TBL_TWR))[tid];
    else if (tid < 128) ((float4*)sm.twi)[tid - 64] = ((const float4*)(tbl + TBL_TWI))[tid - 64];

    float4 w4 = ((const float4*)(tbl + TBL_WIN))[tid];
    float m_a, m_b, m_ny = 0.f, w1r_a, w1i_a, w1r_b, w1i_b;
    {
        const int s0 = t * NBINS;
        if (tid == 0) {
            m_a = magg[s0]; m_ny = magg[s0 + 512]; m_b = magg[s0 + 256];
            w1r_a = 1.f; w1i_a = 0.f; w1r_b = 0.f; w1i_b = 1.f;
        } else {
            m_a = magg[s0 + tid]; m_b = magg[s0 + j2];
            w1r_a = tbl[TBL_W1R + tid]; w1i_a = tbl[TBL_W1I + tid];
            w1r_b = tbl[TBL_W1R + j2];  w1i_b = tbl[TBL_W1I + j2];
        }
    }
    // segment ownership: seg t (lanes 0..63); blocks >=497 also seg t+15 (lanes 64..127)
    const bool extra = (t >= 497);
    int gseg = -1;
    if (tid < 64) gseg = t;
    else if (tid < 128 && extra) gseg = t + 15;
    const int u = tid & 63;
    float iwreg = 0.f;
    if (gseg >= 0) iwreg = iws[(gseg << 6) + u];

    // ---- prologue: x^0 segment(s) from k_init frames ----
    if (gseg >= 0) {
        float acc = 0.f;
#pragma unroll
        for (int m = 0; m < 16; ++m) {
            int tp = gseg - m;
            if (tp >= 0 && tp < NFR)
                acc += coh_load1(&F[(tp << 10) + u + (m << 6)]);
        }
        coh_store1(&X[(gseg << 6) + u], acc * iwreg);
    }
    __syncthreads();                    // drain vmcnt: X^0 at L3
    if (gseg >= 0 && u == 0)
        flag_store(xgen + gseg, 1);     // Xgen[s] = #writes of X[s]

#pragma unroll 1
    for (int it = 1; it <= NITER; ++it) {
        // ---- wait for X^{it-1} of segs [t, t+15] (Xgen >= it) ----
        if (tid < 16) {
            const int s = t + tid;      // <= 526
            while (flag_load(xgen + s) < it)
                __builtin_amdgcn_s_sleep(1);
        }
        __syncthreads();

        // ===== phase A: stft + projection + istft, write frame F[t] =====
        {   // x window * win -> packed z in C1
            float4 xv = coh_load4(&X[(t << 6) + i0]);
            sm.C1r[n0]     = xv.x * w4.x;
            sm.C1i[n0]     = xv.y * w4.y;
            sm.C1r[n0 + 1] = xv.z * w4.z;
            sm.C1i[n0 + 1] = xv.w * w4.w;
        }
        __syncthreads();
        // forward FFT: C1 -> C0
        if (tid < 128) {
            float x0r = sm.C1r[tid],       x0i = sm.C1i[tid];
            float x1r = sm.C1r[tid + 128], x1i = sm.C1i[tid + 128];
            float x2r = sm.C1r[tid + 256], x2i = sm.C1i[tid + 256];
            float x3r = sm.C1r[tid + 384], x3i = sm.C1i[tid + 384];
            float t0r = x0r + x2r, t0i = x0i + x2i;
            float t1r = x0r - x2r, t1i = x0i - x2i;
            float t2r = x1r + x3r, t2i = x1i + x3i;
            float t3r = x1r - x3r, t3i = x1i - x3i;
            float4 vr = make_float4(t0r + t2r, t1r + t3i, t0r - t2r, t1r - t3i);
            float4 vi = make_float4(t0i + t2i, t1i - t3r, t0i - t2i, t1i + t3r);
            ((float4*)sm.C0r)[tid] = vr;
            ((float4*)sm.C0i)[tid] = vi;
        }
        __syncthreads();
        if (tid < 128) r4b<4, 5, false>(sm.C0r, sm.C0i, sm.C1r, sm.C1i, sm.twr, sm.twi, tid);
        __syncthreads();
        if (tid < 128) r4b<16, 3, false>(sm.C1r, sm.C1i, sm.C0r, sm.C0i, sm.twr, sm.twi, tid);
        __syncthreads();
        if (tid < 128) r4b<64, 1, false>(sm.C0r, sm.C0i, sm.C1r, sm.C1i, sm.twr, sm.twi, tid);
        __syncthreads();
        {
            float c = sm.twr[tid], s = sm.twi[tid];
            float x0r = sm.C1r[tid], x0i = sm.C1i[tid];
            float x1r = sm.C1r[tid + 256], x1i = sm.C1i[tid + 256];
            float ar = x1r * c - x1i * s, ai = x1r * s + x1i * c;
            sm.C0r[tid]       = x0r + ar;  sm.C0i[tid]       = x0i + ai;
            sm.C0r[tid + 256] = x0r - ar;  sm.C0i[tid + 256] = x0i - ai;
        }
        __syncthreads();

        // fused unpack + phase projection + iFFT prep: C0 -> C1
        if (tid == 0) {
            float zr = sm.C0r[0], zi = sm.C0i[0];
            float e0 = zr + zi;
            float e5 = zr - zi;
            float X0 = m_a  * e0 / fmaxf(1e-8f, fabsf(e0));
            float X5 = m_ny * e5 / fmaxf(1e-8f, fabsf(e5));
            sm.C1r[0] = (X0 + X5) * (1.0f / 1024.0f);
            sm.C1i[0] = (X0 - X5) * (1.0f / 1024.0f);
            float z6r = sm.C0r[256], z6i = sm.C0i[256];
            float sc6 = m_b / fmaxf(1e-8f, sqrtf(z6r * z6r + z6i * z6i));
            float X6r = z6r * sc6, X6i = -z6i * sc6;
            sm.C1r[256] = X6r * (2.0f / 1024.0f);
            sm.C1i[256] = -X6i * (2.0f / 1024.0f);
        } else {
            float zr = sm.C0r[tid], zi = sm.C0i[tid];
            float ur = sm.C0r[j2],  ui = sm.C0i[j2];
            float er = 0.5f * (zr + ur), ei = 0.5f * (zi - ui);
            float dr = zr - ur,          di = zi + ui;
            float odr = 0.5f * di, odi = -0.5f * dr;
            float e1r = er + w1r_a * odr + w1i_a * odi;
            float e1i = ei + w1r_a * odi - w1i_a * odr;
            float e2r =  er + w1r_b * odr - w1i_b * odi;
            float e2i = -ei - w1r_b * odi - w1i_b * odr;
            float sc1 = m_a / fmaxf(1e-8f, sqrtf(e1r * e1r + e1i * e1i));
            float sc2 = m_b / fmaxf(1e-8f, sqrtf(e2r * e2r + e2i * e2i));
            float X1r = e1r * sc1, X1i = e1i * sc1;
            float X2r = e2r * sc2, X2i = e2i * sc2;
            float Er = X1r + X2r, Ei = X1i - X2i;
            float Dr = X1r - X2r, Di = X1i + X2i;
            float wdr = w1r_a * Dr - w1i_a * Di, wdi = w1r_a * Di + w1i_a * Dr;
            sm.C1r[tid] = (Er - wdi) * (1.0f / 1024.0f);
            sm.C1i[tid] = (Ei + wdr) * (1.0f / 1024.0f);
            float wdr2 = -w1r_b * Dr - w1i_b * Di, wdi2 = w1r_b * Di - w1i_b * Dr;
            sm.C1r[j2] = (Er - wdi2) * (1.0f / 1024.0f);
            sm.C1i[j2] = (-Ei + wdr2) * (1.0f / 1024.0f);
        }
        __syncthreads();

        // inverse FFT: C1 -> C0
        if (tid < 128) {
            float x0r = sm.C1r[tid],       x0i = sm.C1i[tid];
            float x1r = sm.C1r[tid + 128], x1i = sm.C1i[tid + 128];
            float x2r = sm.C1r[tid + 256], x2i = sm.C1i[tid + 256];
            float x3r = sm.C1r[tid + 384], x3i = sm.C1i[tid + 384];
            float t0r = x0r + x2r, t0i = x0i + x2i;
            float t1r = x0r - x2r, t1i = x0i - x2i;
            float t2r = x1r + x3r, t2i = x1i + x3i;
            float t3r = x1r - x3r, t3i = x1i - x3i;
            float4 vr = make_float4(t0r + t2r, t1r - t3i, t0r - t2r, t1r + t3i);
            float4 vi = make_float4(t0i + t2i, t1i + t3r, t0i - t2i, t1i - t3r);
            ((float4*)sm.C0r)[tid] = vr;
            ((float4*)sm.C0i)[tid] = vi;
        }
        __syncthreads();
        if (tid < 128) r4b<4, 5, true>(sm.C0r, sm.C0i, sm.C1r, sm.C1i, sm.twr, sm.twi, tid);
        __syncthreads();
        if (tid < 128) r4b<16, 3, true>(sm.C1r, sm.C1i, sm.C0r, sm.C0i, sm.twr, sm.twi, tid);
        __syncthreads();
        if (tid < 128) r4b<64, 1, true>(sm.C0r, sm.C0i, sm.C1r, sm.C1i, sm.twr, sm.twi, tid);
        __syncthreads();
        {
            float c = sm.twr[tid], s = -sm.twi[tid];
            float x0r = sm.C1r[tid], x0i = sm.C1i[tid];
            float x1r = sm.C1r[tid + 256], x1i = sm.C1i[tid + 256];
            float ar = x1r * c - x1i * s, ai = x1r * s + x1i * c;
            sm.C0r[tid]       = x0r + ar;  sm.C0i[tid]       = x0i + ai;
            sm.C0r[tid + 256] = x0r - ar;  sm.C0i[tid + 256] = x0i - ai;
        }
        __syncthreads();

        // store windowed frame (sc1, at L3), then publish Fgen[t] = it
        {
            float4 o;
            o.x = w4.x * sm.C0r[n0];
            o.y = w4.y * sm.C0i[n0];
            o.z = w4.z * sm.C0r[n0 + 1];
            o.w = w4.w * sm.C0i[n0 + 1];
            coh_store4(&F[(t << 10) + i0], o);
        }
        __syncthreads();                 // drain vmcnt: F[t]@it at L3
        if (tid == 0)
            flag_store(fgen + t, it);

        // ---- wait for the <=16 frames feeding owned segment(s) ----
        if (gseg >= 0 && u < 16) {
            int tp = gseg - u;
            if (tp >= 0 && tp < NFR)
                while (flag_load(fgen + tp) < it)
                    __builtin_amdgcn_s_sleep(1);
        }
        __syncthreads();

        // ===== phase B: OLA own segment(s) =====
        if (gseg >= 0) {
            float acc = 0.f;
#pragma unroll
            for (int m = 0; m < 16; ++m) {
                int tp = gseg - m;
                if (tp >= 0 && tp < NFR)
                    acc += coh_load1(&F[(tp << 10) + u + (m << 6)]);
            }
            float val = acc * iwreg;
            if (it < NITER) coh_store1(&X[(gseg << 6) + u], val);
            else            out[(gseg << 6) + u] = val;
        }
        if (it < NITER) {
            __syncthreads();             // drain vmcnt: X@it at L3
            if (gseg >= 0 && u == 0)
                flag_store(xgen + gseg, it + 1);
        }
    }
}

extern "C" void kernel_launch(void* const* d_in, const int* in_sizes, int n_in,
                              void* d_out, int out_size, void* d_ws, size_t ws_size,
                              hipStream_t stream) {
    const float* mel    = (const float*)d_in[0];
    const float* invmel = (const float*)d_in[1];
    float* out = (float*)d_out;
    float* ws  = (float*)d_ws;

    k_init<<<NFR, NT, 0, stream>>>(mel, invmel, ws);
    k_persist<<<NB, NT, 0, stream>>>(ws, out);
}

// Round 2
// 3483.022 us; speedup vs baseline: 1.1344x; 1.1344x over previous
//
#include <hip/hip_runtime.h>
#include <math.h>

#define NFFT   1024
#define NH     512
#define HOP    64
#define NMELS  80
#define NFR    512
#define NBINS  513
#define NITER  300
#define SIGLEN 33728
#define NSEG   527
#define NT     256
#define NB     512

// ---- workspace layout (4B units) ----
#define TBL_WIN  0          // win[1024]
#define TBL_TWR  1024       // twr[256]
#define TBL_TWI  1280       // twi[256]
#define TBL_W1R  1536       // w1r[513]
#define TBL_W1I  2056       // w1i[513]
#define FGEN     2624       // Fgen[512]  frame-generation flags
#define OFF_MAG  4096       // mag[512*513]
#define OFF_IWS  266752     // iws[33728]
#define OFF_F    300480     // F parity-0 [512*1024]
#define OFF_F2   824768     // F parity-1 [512*1024]

typedef unsigned long long u64;
typedef unsigned int u32;

// ---- coherent (agent-scope sc1, L3-point) accessors ----
__device__ __forceinline__ float4 coh_load4(const float* p) {
    u64 a = __hip_atomic_load((const u64*)p,       __ATOMIC_RELAXED, __HIP_MEMORY_SCOPE_AGENT);
    u64 b = __hip_atomic_load((const u64*)(p + 2), __ATOMIC_RELAXED, __HIP_MEMORY_SCOPE_AGENT);
    float2 fa, fb;
    __builtin_memcpy(&fa, &a, 8);
    __builtin_memcpy(&fb, &b, 8);
    return make_float4(fa.x, fa.y, fb.x, fb.y);
}
__device__ __forceinline__ void coh_store4(float* p, float4 v) {
    float2 fa = make_float2(v.x, v.y), fb = make_float2(v.z, v.w);
    u64 a, b;
    __builtin_memcpy(&a, &fa, 8);
    __builtin_memcpy(&b, &fb, 8);
    __hip_atomic_store((u64*)p,       a, __ATOMIC_RELAXED, __HIP_MEMORY_SCOPE_AGENT);
    __hip_atomic_store((u64*)(p + 2), b, __ATOMIC_RELAXED, __HIP_MEMORY_SCOPE_AGENT);
}
__device__ __forceinline__ float coh_load1(const float* p) {
    u32 a = __hip_atomic_load((const u32*)p, __ATOMIC_RELAXED, __HIP_MEMORY_SCOPE_AGENT);
    float f;
    __builtin_memcpy(&f, &a, 4);
    return f;
}
__device__ __forceinline__ void flag_store(int* p, int v) {
    __hip_atomic_store(p, v, __ATOMIC_RELAXED, __HIP_MEMORY_SCOPE_AGENT);
}
__device__ __forceinline__ int flag_load(const int* p) {
    return __hip_atomic_load(p, __ATOMIC_RELAXED, __HIP_MEMORY_SCOPE_AGENT);
}

// ---- radix-4 Stockham stage (verified), caller guards tid<128 ----
template<int P, int SH, bool INV>
__device__ __forceinline__ void r4b(const float* __restrict__ sR, const float* __restrict__ sI,
                                    float* __restrict__ dR, float* __restrict__ dI,
                                    const float* twr, const float* twi, int j) {
    int k  = j & (P - 1);
    int d0 = ((j - k) << 2) + k;
    float x0r = sR[j],       x0i = sI[j];
    float x1r = sR[j + 128], x1i = sI[j + 128];
    float x2r = sR[j + 256], x2i = sI[j + 256];
    float x3r = sR[j + 384], x3i = sI[j + 384];
    int tb = k << SH;
    float c1 = twr[tb], s1 = twi[tb];
    if (INV) s1 = -s1;
    float c2 = c1 * c1 - s1 * s1, s2 = 2.f * c1 * s1;
    float c3 = c1 * c2 - s1 * s2, s3 = c1 * s2 + s1 * c2;
    float a1r = x1r * c1 - x1i * s1, a1i = x1r * s1 + x1i * c1;
    float a2r = x2r * c2 - x2i * s2, a2i = x2r * s2 + x2i * c2;
    float a3r = x3r * c3 - x3i * s3, a3i = x3r * s3 + x3i * c3;
    float t0r = x0r + a2r, t0i = x0i + a2i;
    float t1r = x0r - a2r, t1i = x0i - a2i;
    float t2r = a1r + a3r, t2i = a1i + a3i;
    float t3r = a1r - a3r, t3i = a1i - a3i;
    float i3r = INV ? -t3i : t3i;
    float i3i = INV ?  t3r : -t3r;
    dR[d0]         = t0r + t2r;  dI[d0]         = t0i + t2i;
    dR[d0 + P]     = t1r + i3r;  dI[d0 + P]     = t1i + i3i;
    dR[d0 + 2 * P] = t0r - t2r;  dI[d0 + 2 * P] = t0i - t2i;
    dR[d0 + 3 * P] = t1r - i3r;  dI[d0 + 3 * P] = t1i - i3i;
}

// ================= k_init (round-3/5 verified) ===============================
struct __align__(16) SMemI {
    float xb[NFFT];
    float C0r[NH], C0i[NH];
    float C1r[NH], C1i[NH];
    float win[NFFT];
    float twr[256], twi[256];
    float mag[516];
};

extern "C" __global__ __launch_bounds__(NT)
void k_init(const float* __restrict__ mel,
            const float* __restrict__ invmel,
            float* __restrict__ ws) {
    __shared__ SMemI sm;
    const int tid = threadIdx.x;
    const int t   = blockIdx.x;

    for (int n = tid; n < NFFT; n += NT) {
        double a = (2.0 * 3.14159265358979323846) * (double)n / 1024.0;
        sm.win[n] = (float)(0.5 - 0.5 * cos(a));
    }
    for (int j = tid; j < 256; j += NT) {
        double a = (2.0 * 3.14159265358979323846) * (double)j / 512.0;
        sm.twr[j] = (float)cos(a);
        sm.twi[j] = (float)(-sin(a));
    }
    __syncthreads();
    if (t == 0) {
        for (int n = tid; n < NFFT; n += NT) ws[TBL_WIN + n] = sm.win[n];
        for (int j = tid; j < 256; j += NT) {
            ws[TBL_TWR + j] = sm.twr[j];
            ws[TBL_TWI + j] = sm.twi[j];
        }
        for (int k = tid; k < NBINS; k += NT) {
            double a = (2.0 * 3.14159265358979323846) * (double)k / 1024.0;
            ws[TBL_W1R + k] = (float)cos(a);
            ws[TBL_W1I + k] = (float)sin(a);
        }
        // zero frame-generation flags (k_init frames are generation 0)
        for (int i = tid; i < NFR; i += NT)
            ((int*)ws)[FGEN + i] = 0;
    }

    for (int p = t * NT + tid; p < SIGLEN; p += NFR * NT) {
        int tq = p >> 6, io = p & 63;
        float s = 0.f;
#pragma unroll
        for (int m = 0; m < 16; ++m) {
            int tp = tq - m;
            if (tp >= 0 && tp < NFR) {
                float w = sm.win[io + (m << 6)];
                s += w * w;
            }
        }
        ws[OFF_IWS + p] = (s > 1e-11f) ? (1.0f / s) : 1.0f;
    }

    if (tid < NMELS) sm.xb[tid] = exp10f(mel[tid * NFR + t]);
    __syncthreads();
    for (int k = tid; k < NBINS; k += NT) {
        const float* row = invmel + k * NMELS;
        float s = 0.f;
#pragma unroll 8
        for (int j = 0; j < NMELS; ++j) s += row[j] * sm.xb[j];
        ws[OFF_MAG + t * NBINS + k] = s;
        sm.mag[k] = s;
    }
    __syncthreads();

    // A[k] from real X = mag
    for (int k = tid; k < NH; k += NT) {
        float xr = sm.mag[k], yr = sm.mag[512 - k];
        double a = (2.0 * 3.14159265358979323846) * (double)k / 1024.0;
        float c = (float)cos(a), s = (float)sin(a);
        float dr = xr - yr;
        sm.C1r[k] = ((xr + yr) - s * dr) * (1.0f / 1024.0f);
        sm.C1i[k] = (c * dr) * (1.0f / 1024.0f);
    }
    // inverse FFT C1 -> C0
    __syncthreads();
    if (tid < 128) {
        float x0r = sm.C1r[tid],       x0i = sm.C1i[tid];
        float x1r = sm.C1r[tid + 128], x1i = sm.C1i[tid + 128];
        float x2r = sm.C1r[tid + 256], x2i = sm.C1i[tid + 256];
        float x3r = sm.C1r[tid + 384], x3i = sm.C1i[tid + 384];
        float t0r = x0r + x2r, t0i = x0i + x2i;
        float t1r = x0r - x2r, t1i = x0i - x2i;
        float t2r = x1r + x3r, t2i = x1i + x3i;
        float t3r = x1r - x3r, t3i = x1i - x3i;
        float4 vr = make_float4(t0r + t2r, t1r - t3i, t0r - t2r, t1r + t3i);
        float4 vi = make_float4(t0i + t2i, t1i + t3r, t0i - t2i, t1i - t3r);
        ((float4*)sm.C0r)[tid] = vr;
        ((float4*)sm.C0i)[tid] = vi;
    }
    __syncthreads();
    if (tid < 128) r4b<4, 5, true>(sm.C0r, sm.C0i, sm.C1r, sm.C1i, sm.twr, sm.twi, tid);
    __syncthreads();
    if (tid < 128) r4b<16, 3, true>(sm.C1r, sm.C1i, sm.C0r, sm.C0i, sm.twr, sm.twi, tid);
    __syncthreads();
    if (tid < 128) r4b<64, 1, true>(sm.C0r, sm.C0i, sm.C1r, sm.C1i, sm.twr, sm.twi, tid);
    __syncthreads();
    {
        float c = sm.twr[tid], s = -sm.twi[tid];
        float x0r = sm.C1r[tid], x0i = sm.C1i[tid];
        float x1r = sm.C1r[tid + 256], x1i = sm.C1i[tid + 256];
        float ar = x1r * c - x1i * s, ai = x1r * s + x1i * c;
        sm.C0r[tid]       = x0r + ar;  sm.C0i[tid]       = x0i + ai;
        sm.C0r[tid + 256] = x0r - ar;  sm.C0i[tid + 256] = x0i - ai;
    }
    __syncthreads();

    float4 w4 = ((float4*)sm.win)[tid];
    float4 o;
    o.x = w4.x * sm.C0r[2 * tid];
    o.y = w4.y * sm.C0i[2 * tid];
    o.z = w4.z * sm.C0r[2 * tid + 1];
    o.w = w4.w * sm.C0i[2 * tid + 1];
    *(float4*)&ws[OFF_F + (t << 10) + (tid << 2)] = o;
}

// ============== persistent Griffin-Lim: FUSED single-flag-round pipeline ====
//
// Each block t computes its OWN windowed OLA input directly from frames
// F[t-15..t+15] (16x redundant gather, 16 float4 L3 loads/thread), removing
// the X array and one full publish->observe round per iteration. F is parity
// double-buffered (F0/F1): iteration it reads parity (it-1)&1, writes parity
// it&1. RAW: fgen[tau] >= it-1 for tau in [t-15,t+15]. WAR: overwriting the
// parity buffer (holds gen it-2) is safe because fgen[tau] >= it-1 implies
// tau finished its it-1 gather (gather precedes F-store within an iteration).
// Dependence graph A(t,it) <- A(t+-15,it-1) is acyclic; flags monotone.
// Final output: one non-redundant per-segment OLA at gen NITER (parity 0).

struct __align__(16) SM1 {
    float C0r[NH], C0i[NH];
    float C1r[NH], C1i[NH];
    float twr[256], twi[256];
};

extern "C" __global__ __launch_bounds__(NT)
void k_persist(float* __restrict__ ws, float* __restrict__ out) {
    __shared__ SM1 sm;
    const int tid = threadIdx.x;
    const int t   = blockIdx.x;       // frame owned
    const int i0  = tid << 2;
    const int j2  = 512 - tid;
    const int n0  = tid << 1;

    const float* tbl  = ws;
    const float* magg = ws + OFF_MAG;
    const float* iws  = ws + OFF_IWS;
    float* F0 = ws + OFF_F;
    float* F1 = ws + OFF_F2;
    int*   fgen = (int*)ws + FGEN;

    // ---- one-time staging ----
    if (tid < 64)       ((float4*)sm.twr)[tid]      = ((const float4*)(tbl + TBL_TWR))[tid];
    else if (tid < 128) ((float4*)sm.twi)[tid - 64] = ((const float4*)(tbl + TBL_TWI))[tid - 64];

    float4 w4   = ((const float4*)(tbl + TBL_WIN))[tid];
    float4 iws4 = *(const float4*)&iws[(t << 6) + i0];   // iws over this block's window
    float m_a, m_b, m_ny = 0.f, w1r_a, w1i_a, w1r_b, w1i_b;
    {
        const int s0 = t * NBINS;
        if (tid == 0) {
            m_a = magg[s0]; m_ny = magg[s0 + 512]; m_b = magg[s0 + 256];
            w1r_a = 1.f; w1i_a = 0.f; w1r_b = 0.f; w1i_b = 1.f;
        } else {
            m_a = magg[s0 + tid]; m_b = magg[s0 + j2];
            w1r_a = tbl[TBL_W1R + tid]; w1i_a = tbl[TBL_W1I + tid];
            w1r_b = tbl[TBL_W1R + j2];  w1i_b = tbl[TBL_W1I + j2];
        }
    }
    // segment ownership for FINAL output only
    const bool extra = (t >= 497);
    int gseg = -1;
    if (tid < 64) gseg = t;
    else if (tid < 128 && extra) gseg = t + 15;
    const int u = tid & 63;
    float iwreg = 0.f;
    if (gseg >= 0) iwreg = iws[(gseg << 6) + u];

    // gather geometry: thread covers samples n = i0..i0+3 of window [64t, 64t+1023]
    const int q    = tid >> 4;        // n >> 6
    const int tq   = t + q;           // base frame for this sample group
    const int foff = i0 & 63;         // offset within frame row group

#pragma unroll 1
    for (int it = 1; it <= NITER; ++it) {
        // ---- wait: frames t-15..t+15 at generation it-1 ----
        if (it > 1 && tid < 31) {
            int tp = t - 15 + tid;
            if (tp >= 0 && tp < NFR)
                while (flag_load(fgen + tp) < it - 1)
                    __builtin_amdgcn_s_sleep(1);
        }
        __syncthreads();

        const float* Fs = (it & 1) ? F0 : F1;   // source parity (it-1)&1
        float*       Fd = (it & 1) ? F1 : F0;   // dest parity it&1

        // ---- fused local OLA gather + iws + window -> packed z in C1 ----
        float4 acc = make_float4(0.f, 0.f, 0.f, 0.f);
#pragma unroll
        for (int m = 0; m < 16; ++m) {
            int tp = tq - m;
            if (tp >= 0 && tp < NFR) {
                float4 v = coh_load4(&Fs[(tp << 10) + foff + (m << 6)]);
                acc.x += v.x; acc.y += v.y; acc.z += v.z; acc.w += v.w;
            }
        }
        {
            float xx = acc.x * iws4.x;
            float xy = acc.y * iws4.y;
            float xz = acc.z * iws4.z;
            float xw = acc.w * iws4.w;
            sm.C1r[n0]     = xx * w4.x;
            sm.C1i[n0]     = xy * w4.y;
            sm.C1r[n0 + 1] = xz * w4.z;
            sm.C1i[n0 + 1] = xw * w4.w;
        }
        __syncthreads();
        // forward FFT: C1 -> C0
        if (tid < 128) {
            float x0r = sm.C1r[tid],       x0i = sm.C1i[tid];
            float x1r = sm.C1r[tid + 128], x1i = sm.C1i[tid + 128];
            float x2r = sm.C1r[tid + 256], x2i = sm.C1i[tid + 256];
            float x3r = sm.C1r[tid + 384], x3i = sm.C1i[tid + 384];
            float t0r = x0r + x2r, t0i = x0i + x2i;
            float t1r = x0r - x2r, t1i = x0i - x2i;
            float t2r = x1r + x3r, t2i = x1i + x3i;
            float t3r = x1r - x3r, t3i = x1i - x3i;
            float4 vr = make_float4(t0r + t2r, t1r + t3i, t0r - t2r, t1r - t3i);
            float4 vi = make_float4(t0i + t2i, t1i - t3r, t0i - t2i, t1i + t3r);
            ((float4*)sm.C0r)[tid] = vr;
            ((float4*)sm.C0i)[tid] = vi;
        }
        __syncthreads();
        if (tid < 128) r4b<4, 5, false>(sm.C0r, sm.C0i, sm.C1r, sm.C1i, sm.twr, sm.twi, tid);
        __syncthreads();
        if (tid < 128) r4b<16, 3, false>(sm.C1r, sm.C1i, sm.C0r, sm.C0i, sm.twr, sm.twi, tid);
        __syncthreads();
        if (tid < 128) r4b<64, 1, false>(sm.C0r, sm.C0i, sm.C1r, sm.C1i, sm.twr, sm.twi, tid);
        __syncthreads();
        {
            float c = sm.twr[tid], s = sm.twi[tid];
            float x0r = sm.C1r[tid], x0i = sm.C1i[tid];
            float x1r = sm.C1r[tid + 256], x1i = sm.C1i[tid + 256];
            float ar = x1r * c - x1i * s, ai = x1r * s + x1i * c;
            sm.C0r[tid]       = x0r + ar;  sm.C0i[tid]       = x0i + ai;
            sm.C0r[tid + 256] = x0r - ar;  sm.C0i[tid + 256] = x0i - ai;
        }
        __syncthreads();

        // fused unpack + phase projection + iFFT prep: C0 -> C1
        if (tid == 0) {
            float zr = sm.C0r[0], zi = sm.C0i[0];
            float e0 = zr + zi;
            float e5 = zr - zi;
            float X0 = m_a  * e0 / fmaxf(1e-8f, fabsf(e0));
            float X5 = m_ny * e5 / fmaxf(1e-8f, fabsf(e5));
            sm.C1r[0] = (X0 + X5) * (1.0f / 1024.0f);
            sm.C1i[0] = (X0 - X5) * (1.0f / 1024.0f);
            float z6r = sm.C0r[256], z6i = sm.C0i[256];
            float sc6 = m_b / fmaxf(1e-8f, sqrtf(z6r * z6r + z6i * z6i));
            float X6r = z6r * sc6, X6i = -z6i * sc6;
            sm.C1r[256] = X6r * (2.0f / 1024.0f);
            sm.C1i[256] = -X6i * (2.0f / 1024.0f);
        } else {
            float zr = sm.C0r[tid], zi = sm.C0i[tid];
            float ur = sm.C0r[j2],  ui = sm.C0i[j2];
            float er = 0.5f * (zr + ur), ei = 0.5f * (zi - ui);
            float dr = zr - ur,          di = zi + ui;
            float odr = 0.5f * di, odi = -0.5f * dr;
            float e1r = er + w1r_a * odr + w1i_a * odi;
            float e1i = ei + w1r_a * odi - w1i_a * odr;
            float e2r =  er + w1r_b * odr - w1i_b * odi;
            float e2i = -ei - w1r_b * odi - w1i_b * odr;
            float sc1 = m_a / fmaxf(1e-8f, sqrtf(e1r * e1r + e1i * e1i));
            float sc2 = m_b / fmaxf(1e-8f, sqrtf(e2r * e2r + e2i * e2i));
            float X1r = e1r * sc1, X1i = e1i * sc1;
            float X2r = e2r * sc2, X2i = e2i * sc2;
            float Er = X1r + X2r, Ei = X1i - X2i;
            float Dr = X1r - X2r, Di = X1i + X2i;
            float wdr = w1r_a * Dr - w1i_a * Di, wdi = w1r_a * Di + w1i_a * Dr;
            sm.C1r[tid] = (Er - wdi) * (1.0f / 1024.0f);
            sm.C1i[tid] = (Ei + wdr) * (1.0f / 1024.0f);
            float wdr2 = -w1r_b * Dr - w1i_b * Di, wdi2 = w1r_b * Di - w1i_b * Dr;
            sm.C1r[j2] = (Er - wdi2) * (1.0f / 1024.0f);
            sm.C1i[j2] = (-Ei + wdr2) * (1.0f / 1024.0f);
        }
        __syncthreads();

        // inverse FFT: C1 -> C0
        if (tid < 128) {
            float x0r = sm.C1r[tid],       x0i = sm.C1i[tid];
            float x1r = sm.C1r[tid + 128], x1i = sm.C1i[tid + 128];
            float x2r = sm.C1r[tid + 256], x2i = sm.C1i[tid + 256];
            float x3r = sm.C1r[tid + 384], x3i = sm.C1i[tid + 384];
            float t0r = x0r + x2r, t0i = x0i + x2i;
            float t1r = x0r - x2r, t1i = x0i - x2i;
            float t2r = x1r + x3r, t2i = x1i + x3i;
            float t3r = x1r - x3r, t3i = x1i - x3i;
            float4 vr = make_float4(t0r + t2r, t1r - t3i, t0r - t2r, t1r + t3i);
            float4 vi = make_float4(t0i + t2i, t1i + t3r, t0i - t2i, t1i - t3r);
            ((float4*)sm.C0r)[tid] = vr;
            ((float4*)sm.C0i)[tid] = vi;
        }
        __syncthreads();
        if (tid < 128) r4b<4, 5, true>(sm.C0r, sm.C0i, sm.C1r, sm.C1i, sm.twr, sm.twi, tid);
        __syncthreads();
        if (tid < 128) r4b<16, 3, true>(sm.C1r, sm.C1i, sm.C0r, sm.C0i, sm.twr, sm.twi, tid);
        __syncthreads();
        if (tid < 128) r4b<64, 1, true>(sm.C0r, sm.C0i, sm.C1r, sm.C1i, sm.twr, sm.twi, tid);
        __syncthreads();
        {
            float c = sm.twr[tid], s = -sm.twi[tid];
            float x0r = sm.C1r[tid], x0i = sm.C1i[tid];
            float x1r = sm.C1r[tid + 256], x1i = sm.C1i[tid + 256];
            float ar = x1r * c - x1i * s, ai = x1r * s + x1i * c;
            sm.C0r[tid]       = x0r + ar;  sm.C0i[tid]       = x0i + ai;
            sm.C0r[tid + 256] = x0r - ar;  sm.C0i[tid + 256] = x0i - ai;
        }
        __syncthreads();

        // store windowed frame into dest parity (sc1, at L3), publish fgen[t]=it
        {
            float4 o;
            o.x = w4.x * sm.C0r[n0];
            o.y = w4.y * sm.C0i[n0];
            o.z = w4.z * sm.C0r[n0 + 1];
            o.w = w4.w * sm.C0i[n0 + 1];
            coh_store4(&Fd[(t << 10) + i0], o);
        }
        __syncthreads();                 // drain vmcnt: F[t]@it at L3
        if (tid == 0)
            flag_store(fgen + t, it);
    }

    // ===== final non-redundant OLA @ gen NITER (even -> parity 0 -> F0) =====
    if (gseg >= 0 && u < 16) {
        int tp = gseg - u;
        if (tp >= 0 && tp < NFR)
            while (flag_load(fgen + tp) < NITER)
                __builtin_amdgcn_s_sleep(1);
    }
    __syncthreads();
    if (gseg >= 0) {
        float acc = 0.f;
#pragma unroll
        for (int m = 0; m < 16; ++m) {
            int tp = gseg - m;
            if (tp >= 0 && tp < NFR)
                acc += coh_load1(&F0[(tp << 10) + u + (m << 6)]);
        }
        out[(gseg << 6) + u] = acc * iwreg;
    }
}

extern "C" void kernel_launch(void* const* d_in, const int* in_sizes, int n_in,
                              void* d_out, int out_size, void* d_ws, size_t ws_size,
                              hipStream_t stream) {
    const float* mel    = (const float*)d_in[0];
    const float* invmel = (const float*)d_in[1];
    float* out = (float*)d_out;
    float* ws  = (float*)d_ws;

    k_init<<<NFR, NT, 0, stream>>>(mel, invmel, ws);
    k_persist<<<NB, NT, 0, stream>>>(ws, out);
}